// Round 13
// baseline (261.470 us; speedup 1.0000x reference)
//
#include <hip/hip_runtime.h>
#include <hip/hip_bf16.h>
#include <math.h>

// ---------------------------------------------------------------------------
// GNN link predictor: 2-layer GraphSAGE (mean agg) + dot-product + sigmoid.
//  - transform-then-aggregate (mean is linear) -> aggregate in 64-dim space
//  - GEMMs on MFMA (16x16x32 bf16, fp32 accum), W read f32 + packed to
//    register-resident bf16 B-frags in-kernel (no cast kernel)
//  - CSR build: 2-level LDS counting sort (bucket = dst>>8), ZERO global
//    atomics (R6/R7: returning device atomics = 24.6G/s HW wall). G_BLK=512.
//  - root path Q stored bf16; gathers uint4 (8 lanes x 16B = one 128B row)
//  - R12: packed cvt (v_cvt_pk_f32_bf16) + float2 accumulators
//  - R13: k_agg neighbor loop unrolled 8 (+2-deep mid loop) — aggs are
//    latency-bound (7.5 TB/s vs ~16 TB/s L2/L3 mix); 8 uint4 in flight
//    per lane doubles outstanding misses.
// ---------------------------------------------------------------------------

#define HID 64
#define G_BLK 512   // blocks in bucket passes A/C
#define NB_MAX 512  // max buckets of 256 nodes (N <= 131072)

typedef __attribute__((ext_vector_type(8))) short short8;   // 8 bf16 (4 VGPR)
typedef __attribute__((ext_vector_type(4))) float floatx4;  // MFMA acc

__device__ __forceinline__ unsigned short f2bf(float f) {
    union { float f; unsigned u; } v; v.f = f;
    unsigned r = v.u + 0x7FFF + ((v.u >> 16) & 1);  // round-to-nearest-even
    return (unsigned short)(r >> 16);
}
__device__ __forceinline__ unsigned pack_bf2(float a, float b) {
    union { __hip_bfloat162 h; unsigned u; } cv;
    cv.h = __float22bfloat162_rn(make_float2(a, b));  // v_cvt_pk_bf16_f32
    return cv.u;
}
__device__ __forceinline__ float2 bfx2(unsigned u) {  // v_cvt_pk_f32_bf16
    union { unsigned u; __hip_bfloat162 h; } cv; cv.u = u;
    return __bfloat1622float2(cv.h);
}
// accumulate one bf16x8 row (uint4) into 4 float2 accumulators
__device__ __forceinline__ void accp(float2* a, uint4 u) {
    float2 f0 = bfx2(u.x), f1 = bfx2(u.y), f2 = bfx2(u.z), f3 = bfx2(u.w);
    a[0].x += f0.x; a[0].y += f0.y;
    a[1].x += f1.x; a[1].y += f1.y;
    a[2].x += f2.x; a[2].y += f2.y;
    a[3].x += f3.x; a[3].y += f3.y;
}

// ---------------- CSR build: 2-level LDS counting sort ----------------

// Pass A: per-block LDS histogram over buckets (dst>>8). cnt[k*G_BLK + b].
__global__ __launch_bounds__(256)
void k_bhist(const int* __restrict__ edst, int* __restrict__ cnt,
             int E, int NB, int CH) {
    __shared__ int lh[NB_MAX];
    const int b = blockIdx.x;
    for (int i = threadIdx.x; i < NB; i += 256) lh[i] = 0;
    __syncthreads();
    const int e0 = b * CH;
    const int e1 = min(E, e0 + CH);
    for (int e = e0 + threadIdx.x; e < e1; e += 256)
        atomicAdd(&lh[edst[e] >> 8], 1);  // LDS atomic
    __syncthreads();
    for (int k = threadIdx.x; k < NB; k += 256)
        cnt[(size_t)k * G_BLK + b] = lh[k];
}

// Pass B1: per-bucket exclusive scan over the G_BLK block counts (wave/bucket).
__global__ __launch_bounds__(256)
void k_bscan1(int* __restrict__ cnt, int* __restrict__ total, int NB) {
    int k = blockIdx.x * 4 + (threadIdx.x >> 6);
    int lane = threadIdx.x & 63;
    if (k >= NB) return;
    int* row = cnt + (size_t)k * G_BLK;
    const int base = lane * 8;  // 8 consecutive blocks per lane
    int v[8];
#pragma unroll
    for (int j = 0; j < 8; ++j) v[j] = row[base + j];
    int s = 0;
#pragma unroll
    for (int j = 0; j < 8; ++j) s += v[j];
    int inc = s;
#pragma unroll
    for (int off = 1; off < 64; off <<= 1) {
        int o = __shfl_up(inc, off, 64);
        if (lane >= off) inc += o;
    }
    int run = inc - s;  // exclusive prefix of this lane's chunk
#pragma unroll
    for (int j = 0; j < 8; ++j) { int t = v[j]; row[base + j] = run; run += t; }
    if (lane == 63) total[k] = run;
}

// Pass B2: exclusive scan of bucket totals -> base. One block, 512 threads.
__global__ __launch_bounds__(512)
void k_bscan2(const int* __restrict__ total, int* __restrict__ base, int NB) {
    __shared__ int lds[512];
    int t = threadIdx.x;
    int v = (t < NB) ? total[t] : 0;
    lds[t] = v;
    __syncthreads();
    for (int off = 1; off < 512; off <<= 1) {
        int x = (t >= off) ? lds[t - off] : 0;
        __syncthreads();
        lds[t] += x;
        __syncthreads();
    }
    if (t < NB) base[t] = lds[t] - v;
}

// Pass C: scatter edges into bucket segments via LDS cursors (no global atomics).
// payload = (dst&255)<<24 | src  (src < 2^24).
__global__ __launch_bounds__(256)
void k_bscatter(const int* __restrict__ esrc, const int* __restrict__ edst,
                const int* __restrict__ cnt, const int* __restrict__ base,
                int* __restrict__ ebuf, int E, int NB, int CH) {
    __shared__ int cur[NB_MAX];
    const int b = blockIdx.x;
    for (int k = threadIdx.x; k < NB; k += 256)
        cur[k] = base[k] + cnt[(size_t)k * G_BLK + b];
    __syncthreads();
    const int e0 = b * CH;
    const int e1 = min(E, e0 + CH);
    for (int e = e0 + threadIdx.x; e < e1; e += 256) {
        int d = edst[e];
        int slot = atomicAdd(&cur[d >> 8], 1);  // LDS atomic
        ebuf[slot] = ((d & 255) << 24) | esrc[e];
    }
}

// Pass D: per-bucket local counting sort -> sorted[], deg[], offs[].
__global__ __launch_bounds__(256)
void k_bfinal(const int* __restrict__ ebuf, const int* __restrict__ total,
              const int* __restrict__ base, int* __restrict__ sorted,
              int* __restrict__ deg, int* __restrict__ offs, int N) {
    __shared__ int h[256], loc[256], cur[256], sc[256];
    const int k = blockIdx.x;
    const int t = threadIdx.x;
    const int nk = total[k];
    const int bs = base[k];
    h[t] = 0;
    __syncthreads();
    for (int i = bs + t; i < bs + nk; i += 256)
        atomicAdd(&h[(ebuf[i] >> 24) & 255], 1);
    __syncthreads();
    int v = h[t];
    sc[t] = v;
    __syncthreads();
    for (int off = 1; off < 256; off <<= 1) {
        int x = (t >= off) ? sc[t - off] : 0;
        __syncthreads();
        sc[t] += x;
        __syncthreads();
    }
    loc[t] = sc[t] - v;
    cur[t] = sc[t] - v;
    __syncthreads();
    for (int i = bs + t; i < bs + nk; i += 256) {
        int pk = ebuf[i];
        int j = (pk >> 24) & 255;
        int r = atomicAdd(&cur[j], 1);  // LDS atomic
        sorted[bs + r] = pk & 0xFFFFFF;
    }
    int node = (k << 8) + t;
    if (node < N) {
        deg[node] = v;
        offs[node] = bs + loc[t];
    }
}

// ---------------- MFMA dual GEMM: [P|Q] = A @ [Wl;Wr]^T ----------------
// Wave computes 16 rows x 64 cols (half=0 -> P, half=1 -> Q), both bf16 out.
// B-frags: read f32 W rows once per wave, pack to bf16 registers.
// A is f32 (layer 1, cvt in-flight) or bf16 (layer 2).

template <int K, bool AF32>
__global__ __launch_bounds__(256, 2)
void gemm_mfma(const void* __restrict__ Xv, const float* __restrict__ Wl,
               const float* __restrict__ Wr, unsigned short* __restrict__ Pb,
               unsigned short* __restrict__ Qb, int N) {
    const int lane = threadIdx.x & 63;
    const int m = lane & 15;        // row (A) / col (B) within tile
    const int q = lane >> 4;        // k-quad
    const int gw = blockIdx.x * 4 + (threadIdx.x >> 6);
    const int half = gw & 1;        // 0 -> P, 1 -> Q
    constexpr int KB = K / 32;

    const float* Wh = half ? Wr : Wl;
    short8 bf[KB][4];
#pragma unroll
    for (int kb = 0; kb < KB; ++kb)
#pragma unroll
        for (int ct = 0; ct < 4; ++ct) {
            int c = ct * 16 + m;
            const float* wp = Wh + (size_t)c * K + kb * 32 + q * 8;
            float4 w0 = *(const float4*)wp;
            float4 w1 = *(const float4*)(wp + 4);
            union { unsigned u[4]; short8 s; } cv;
            cv.u[0] = pack_bf2(w0.x, w0.y);
            cv.u[1] = pack_bf2(w0.z, w0.w);
            cv.u[2] = pack_bf2(w1.x, w1.y);
            cv.u[3] = pack_bf2(w1.z, w1.w);
            bf[kb][ct] = cv.s;
        }

    unsigned short* dstp = half ? Qb : Pb;
    const int ntiles = (N + 15) >> 4;
    const int stride = gridDim.x * 2;  // waves per half
    for (int t = gw >> 1; t < ntiles; t += stride) {
        const int r0 = t << 4;
        int rr = r0 + m;
        if (rr >= N) rr = N - 1;
        floatx4 acc[4];
#pragma unroll
        for (int ct = 0; ct < 4; ++ct) acc[ct] = (floatx4){0.f, 0.f, 0.f, 0.f};

#pragma unroll
        for (int kb = 0; kb < KB; ++kb) {
            short8 a;
            if (AF32) {
                const float* xp = (const float*)Xv + (size_t)rr * K + kb * 32 + q * 8;
                float4 x0 = *(const float4*)xp;
                float4 x1 = *(const float4*)(xp + 4);
                union { unsigned u[4]; short8 s; } cv;
                cv.u[0] = pack_bf2(x0.x, x0.y);
                cv.u[1] = pack_bf2(x0.z, x0.w);
                cv.u[2] = pack_bf2(x1.x, x1.y);
                cv.u[3] = pack_bf2(x1.z, x1.w);
                a = cv.s;
            } else {
                a = *(const short8*)((const unsigned short*)Xv + (size_t)rr * K + kb * 32 + q * 8);
            }
#pragma unroll
            for (int ct = 0; ct < 4; ++ct)
                acc[ct] = __builtin_amdgcn_mfma_f32_16x16x32_bf16(a, bf[kb][ct], acc[ct], 0, 0, 0);
        }

        // C/D: col = ct*16 + m, row = r0 + q*4 + i
#pragma unroll
        for (int i = 0; i < 4; ++i) {
            int row = r0 + q * 4 + i;
            if (row < N) {
#pragma unroll
                for (int ct = 0; ct < 4; ++ct)
                    dstp[(size_t)row * HID + ct * 16 + m] = f2bf(acc[ct][i]);
            }
        }
    }
}

// ------- aggregation: H = relu(mean_{s in N(n)} P[s] + bias + Q[n]) -------
// 8 nodes per wave (8 lanes/node), lane = uint4 = 8 bf16 channels.
// Packed cvt + float2 accumulators; neighbor loop unrolled 8 (R13) for MLP.

__global__ __launch_bounds__(256)
void k_agg(const uint4* __restrict__ P8, const uint2* __restrict__ Qb4,
           const float4* __restrict__ bias4, const int* __restrict__ offs,
           const int* __restrict__ deg, const int* __restrict__ sorted,
           uint4* __restrict__ H8, int N) {
    int node = blockIdx.x * 32 + (threadIdx.x >> 3);
    int c8 = threadIdx.x & 7;
    if (node >= N) return;
    int off = offs[node];
    int c = deg[node];
    float2 a[4];
#pragma unroll
    for (int j = 0; j < 4; ++j) a[j] = make_float2(0.f, 0.f);
    int i = 0;
    for (; i + 7 < c; i += 8) {
        int s[8];
#pragma unroll
        for (int j = 0; j < 8; ++j) s[j] = sorted[off + i + j];
        uint4 u[8];
#pragma unroll
        for (int j = 0; j < 8; ++j) u[j] = P8[(size_t)s[j] * 8 + c8];
#pragma unroll
        for (int j = 0; j < 8; ++j) accp(a, u[j]);
    }
    for (; i + 1 < c; i += 2) {
        int s0 = sorted[off + i];
        int s1 = sorted[off + i + 1];
        uint4 u0 = P8[(size_t)s0 * 8 + c8];
        uint4 u1 = P8[(size_t)s1 * 8 + c8];
        accp(a, u0); accp(a, u1);
    }
    if (i < c) accp(a, P8[(size_t)sorted[off + i] * 8 + c8]);

    float inv = 1.0f / (float)(c > 0 ? c : 1);
    float4 b0 = bias4[c8 * 2], b1 = bias4[c8 * 2 + 1];
    uint2 q0 = Qb4[(size_t)node * 16 + c8 * 2];
    uint2 q1 = Qb4[(size_t)node * 16 + c8 * 2 + 1];
    float2 r0 = bfx2(q0.x), r1 = bfx2(q0.y), r2 = bfx2(q1.x), r3 = bfx2(q1.y);
    float v0 = a[0].x * inv + b0.x + r0.x;
    float v1 = a[0].y * inv + b0.y + r0.y;
    float v2 = a[1].x * inv + b0.z + r1.x;
    float v3 = a[1].y * inv + b0.w + r1.y;
    float v4 = a[2].x * inv + b1.x + r2.x;
    float v5 = a[2].y * inv + b1.y + r2.y;
    float v6 = a[3].x * inv + b1.z + r3.x;
    float v7 = a[3].y * inv + b1.w + r3.y;
    v0 = fmaxf(v0, 0.f); v1 = fmaxf(v1, 0.f); v2 = fmaxf(v2, 0.f); v3 = fmaxf(v3, 0.f);
    v4 = fmaxf(v4, 0.f); v5 = fmaxf(v5, 0.f); v6 = fmaxf(v6, 0.f); v7 = fmaxf(v7, 0.f);
    uint4 hp;
    hp.x = pack_bf2(v0, v1);
    hp.y = pack_bf2(v2, v3);
    hp.z = pack_bf2(v4, v5);
    hp.w = pack_bf2(v6, v7);
    H8[(size_t)node * 8 + c8] = hp;
}

// ---------------- query: out[q] = sigmoid(sum_c Z[s][c]*Z[d][c]) ----------------
// 8 queries per wave (8 lanes each), uint4 bf16x8 loads, packed cvt + fma.

__global__ __launch_bounds__(256)
void k_query(const uint4* __restrict__ Z8, const int* __restrict__ src,
             const int* __restrict__ dst, float* __restrict__ out, int Q) {
    int qi = blockIdx.x * 32 + (threadIdx.x >> 3);
    int c8 = threadIdx.x & 7;
    if (qi >= Q) return;
    int s = src[qi];
    int d = dst[qi];
    uint4 us = Z8[(size_t)s * 8 + c8];
    uint4 ud = Z8[(size_t)d * 8 + c8];
    float2 p0 = bfx2(us.x), p1 = bfx2(us.y), p2 = bfx2(us.z), p3 = bfx2(us.w);
    float2 t0 = bfx2(ud.x), t1 = bfx2(ud.y), t2 = bfx2(ud.z), t3 = bfx2(ud.w);
    float2 acc2 = make_float2(p0.x * t0.x, p0.y * t0.y);
    acc2.x = fmaf(p1.x, t1.x, acc2.x); acc2.y = fmaf(p1.y, t1.y, acc2.y);
    acc2.x = fmaf(p2.x, t2.x, acc2.x); acc2.y = fmaf(p2.y, t2.y, acc2.y);
    acc2.x = fmaf(p3.x, t3.x, acc2.x); acc2.y = fmaf(p3.y, t3.y, acc2.y);
    float v = acc2.x + acc2.y;
#pragma unroll
    for (int mres = 4; mres > 0; mres >>= 1) v += __shfl_xor(v, mres, 64);
    if (c8 == 0) out[qi] = 1.0f / (1.0f + __expf(-v));
}

// ---------------- launch ----------------

extern "C" void kernel_launch(void* const* d_in, const int* in_sizes, int n_in,
                              void* d_out, int out_size, void* d_ws, size_t ws_size,
                              hipStream_t stream) {
    const float* x    = (const float*)d_in[0];
    const int*   ei   = (const int*)d_in[1];
    const int*   qsrc = (const int*)d_in[2];
    const int*   qdst = (const int*)d_in[3];
    const float* Wl1  = (const float*)d_in[4];
    const float* bl1  = (const float*)d_in[5];
    const float* Wr1  = (const float*)d_in[6];
    const float* Wl2  = (const float*)d_in[7];
    const float* bl2  = (const float*)d_in[8];
    const float* Wr2  = (const float*)d_in[9];
    float* out = (float*)d_out;

    const int N = in_sizes[0] / 128;  // IN_CH = 128
    const int E = in_sizes[1] / 2;
    const int Q = in_sizes[2];

    const int* esrc = ei;
    const int* edst = ei + E;

    // workspace layout (no aliasing; ws is plenty)
    unsigned short* Pb = (unsigned short*)d_ws;         // N x 64 bf16 messages
    unsigned short* Qb = Pb + (size_t)N * HID;          // N x 64 bf16 root
    unsigned short* Hb = Qb + (size_t)N * HID;          // N x 64 bf16 h
    unsigned short* Zb = Hb + (size_t)N * HID;          // N x 64 bf16 z
    int* deg_c  = (int*)(Zb + (size_t)N * HID);         // N
    int* offs   = deg_c + N;                            // N
    int* total  = offs + N;                             // NB_MAX
    int* base   = total + NB_MAX;                       // NB_MAX
    int* sorted = base + NB_MAX;                        // E
    int* cnt    = sorted + E;                           // NB_MAX*G_BLK
    int* ebuf   = cnt + (size_t)NB_MAX * G_BLK;         // E

    const int NB = (N + 255) >> 8;            // buckets of 256 nodes (<= NB_MAX)
    const int CH = (E + G_BLK - 1) / G_BLK;   // edges per bucket-pass block
    const int gG = 640;                       // grid-stride MFMA gemm
    const int gA = (N + 31) / 32;             // 8 nodes/wave, 4 waves/block
    const int gQ = (Q + 31) / 32;

    // CSR build: zero global atomics
    k_bhist<<<G_BLK, 256, 0, stream>>>(edst, cnt, E, NB, CH);
    k_bscan1<<<(NB + 3) / 4, 256, 0, stream>>>(cnt, total, NB);
    k_bscan2<<<1, 512, 0, stream>>>(total, base, NB);
    k_bscatter<<<G_BLK, 256, 0, stream>>>(esrc, edst, cnt, base, ebuf, E, NB, CH);
    k_bfinal<<<NB, 256, 0, stream>>>(ebuf, total, base, sorted, deg_c, offs, N);

    // layer 1: Pb = bf16(x@Wl1^T), Qb = bf16(x@Wr1^T); Hb = bf16(relu(mean+b+Qb))
    gemm_mfma<128, true><<<gG, 256, 0, stream>>>(x, Wl1, Wr1, Pb, Qb, N);
    k_agg<<<gA, 256, 0, stream>>>((const uint4*)Pb, (const uint2*)Qb,
                                  (const float4*)bl1, offs, deg_c, sorted,
                                  (uint4*)Hb, N);

    // layer 2: Pb = bf16(Hb@Wl2^T), Qb = bf16(Hb@Wr2^T); Zb = bf16(relu(mean+b+Qb))
    gemm_mfma<64, false><<<gG, 256, 0, stream>>>(Hb, Wl2, Wr2, Pb, Qb, N);
    k_agg<<<gA, 256, 0, stream>>>((const uint4*)Pb, (const uint2*)Qb,
                                  (const float4*)bl2, offs, deg_c, sorted,
                                  (uint4*)Zb, N);

    // queries
    k_query<<<gQ, 256, 0, stream>>>((const uint4*)Zb, qsrc, qdst, out, Q);
}

// Round 14
// 255.395 us; speedup vs baseline: 1.0238x; 1.0238x over previous
//
#include <hip/hip_runtime.h>
#include <hip/hip_bf16.h>
#include <math.h>

// ---------------------------------------------------------------------------
// GNN link predictor: 2-layer GraphSAGE (mean agg) + dot-product + sigmoid.
// FINAL (R12 config — best measured 255.8us):
//  - transform-then-aggregate (mean is linear) -> aggregate in 64-dim space
//  - GEMMs on MFMA (16x16x32 bf16, fp32 accum), W read f32 + packed to
//    register-resident bf16 B-frags in-kernel
//  - CSR build: 2-level LDS counting sort (bucket = dst>>8), ZERO global
//    atomics (R6/R7: returning device atomics = 24.6G/s HW wall). G_BLK=512.
//  - root path Q stored bf16; gathers uint4 (8 lanes x 16B = one 128B row)
//  - packed cvt (v_cvt_pk_f32_bf16) + float2 accumulators, 4-deep unroll
//    (R13 showed 8-deep regresses: aggs are at the cache-subsystem floor)
// ---------------------------------------------------------------------------

#define HID 64
#define G_BLK 512   // blocks in bucket passes A/C
#define NB_MAX 512  // max buckets of 256 nodes (N <= 131072)

typedef __attribute__((ext_vector_type(8))) short short8;   // 8 bf16 (4 VGPR)
typedef __attribute__((ext_vector_type(4))) float floatx4;  // MFMA acc

__device__ __forceinline__ unsigned short f2bf(float f) {
    union { float f; unsigned u; } v; v.f = f;
    unsigned r = v.u + 0x7FFF + ((v.u >> 16) & 1);  // round-to-nearest-even
    return (unsigned short)(r >> 16);
}
__device__ __forceinline__ unsigned pack_bf2(float a, float b) {
    union { __hip_bfloat162 h; unsigned u; } cv;
    cv.h = __float22bfloat162_rn(make_float2(a, b));  // v_cvt_pk_bf16_f32
    return cv.u;
}
__device__ __forceinline__ float2 bfx2(unsigned u) {  // v_cvt_pk_f32_bf16
    union { unsigned u; __hip_bfloat162 h; } cv; cv.u = u;
    return __bfloat1622float2(cv.h);
}
// accumulate one bf16x8 row (uint4) into 4 float2 accumulators
__device__ __forceinline__ void accp(float2* a, uint4 u) {
    float2 f0 = bfx2(u.x), f1 = bfx2(u.y), f2 = bfx2(u.z), f3 = bfx2(u.w);
    a[0].x += f0.x; a[0].y += f0.y;
    a[1].x += f1.x; a[1].y += f1.y;
    a[2].x += f2.x; a[2].y += f2.y;
    a[3].x += f3.x; a[3].y += f3.y;
}

// ---------------- CSR build: 2-level LDS counting sort ----------------

// Pass A: per-block LDS histogram over buckets (dst>>8). cnt[k*G_BLK + b].
__global__ __launch_bounds__(256)
void k_bhist(const int* __restrict__ edst, int* __restrict__ cnt,
             int E, int NB, int CH) {
    __shared__ int lh[NB_MAX];
    const int b = blockIdx.x;
    for (int i = threadIdx.x; i < NB; i += 256) lh[i] = 0;
    __syncthreads();
    const int e0 = b * CH;
    const int e1 = min(E, e0 + CH);
    for (int e = e0 + threadIdx.x; e < e1; e += 256)
        atomicAdd(&lh[edst[e] >> 8], 1);  // LDS atomic
    __syncthreads();
    for (int k = threadIdx.x; k < NB; k += 256)
        cnt[(size_t)k * G_BLK + b] = lh[k];
}

// Pass B1: per-bucket exclusive scan over the G_BLK block counts (wave/bucket).
__global__ __launch_bounds__(256)
void k_bscan1(int* __restrict__ cnt, int* __restrict__ total, int NB) {
    int k = blockIdx.x * 4 + (threadIdx.x >> 6);
    int lane = threadIdx.x & 63;
    if (k >= NB) return;
    int* row = cnt + (size_t)k * G_BLK;
    const int base = lane * 8;  // 8 consecutive blocks per lane
    int v[8];
#pragma unroll
    for (int j = 0; j < 8; ++j) v[j] = row[base + j];
    int s = 0;
#pragma unroll
    for (int j = 0; j < 8; ++j) s += v[j];
    int inc = s;
#pragma unroll
    for (int off = 1; off < 64; off <<= 1) {
        int o = __shfl_up(inc, off, 64);
        if (lane >= off) inc += o;
    }
    int run = inc - s;  // exclusive prefix of this lane's chunk
#pragma unroll
    for (int j = 0; j < 8; ++j) { int t = v[j]; row[base + j] = run; run += t; }
    if (lane == 63) total[k] = run;
}

// Pass B2: exclusive scan of bucket totals -> base. One block, 512 threads.
__global__ __launch_bounds__(512)
void k_bscan2(const int* __restrict__ total, int* __restrict__ base, int NB) {
    __shared__ int lds[512];
    int t = threadIdx.x;
    int v = (t < NB) ? total[t] : 0;
    lds[t] = v;
    __syncthreads();
    for (int off = 1; off < 512; off <<= 1) {
        int x = (t >= off) ? lds[t - off] : 0;
        __syncthreads();
        lds[t] += x;
        __syncthreads();
    }
    if (t < NB) base[t] = lds[t] - v;
}

// Pass C: scatter edges into bucket segments via LDS cursors (no global atomics).
// payload = (dst&255)<<24 | src  (src < 2^24).
__global__ __launch_bounds__(256)
void k_bscatter(const int* __restrict__ esrc, const int* __restrict__ edst,
                const int* __restrict__ cnt, const int* __restrict__ base,
                int* __restrict__ ebuf, int E, int NB, int CH) {
    __shared__ int cur[NB_MAX];
    const int b = blockIdx.x;
    for (int k = threadIdx.x; k < NB; k += 256)
        cur[k] = base[k] + cnt[(size_t)k * G_BLK + b];
    __syncthreads();
    const int e0 = b * CH;
    const int e1 = min(E, e0 + CH);
    for (int e = e0 + threadIdx.x; e < e1; e += 256) {
        int d = edst[e];
        int slot = atomicAdd(&cur[d >> 8], 1);  // LDS atomic
        ebuf[slot] = ((d & 255) << 24) | esrc[e];
    }
}

// Pass D: per-bucket local counting sort -> sorted[], deg[], offs[].
__global__ __launch_bounds__(256)
void k_bfinal(const int* __restrict__ ebuf, const int* __restrict__ total,
              const int* __restrict__ base, int* __restrict__ sorted,
              int* __restrict__ deg, int* __restrict__ offs, int N) {
    __shared__ int h[256], loc[256], cur[256], sc[256];
    const int k = blockIdx.x;
    const int t = threadIdx.x;
    const int nk = total[k];
    const int bs = base[k];
    h[t] = 0;
    __syncthreads();
    for (int i = bs + t; i < bs + nk; i += 256)
        atomicAdd(&h[(ebuf[i] >> 24) & 255], 1);
    __syncthreads();
    int v = h[t];
    sc[t] = v;
    __syncthreads();
    for (int off = 1; off < 256; off <<= 1) {
        int x = (t >= off) ? sc[t - off] : 0;
        __syncthreads();
        sc[t] += x;
        __syncthreads();
    }
    loc[t] = sc[t] - v;
    cur[t] = sc[t] - v;
    __syncthreads();
    for (int i = bs + t; i < bs + nk; i += 256) {
        int pk = ebuf[i];
        int j = (pk >> 24) & 255;
        int r = atomicAdd(&cur[j], 1);  // LDS atomic
        sorted[bs + r] = pk & 0xFFFFFF;
    }
    int node = (k << 8) + t;
    if (node < N) {
        deg[node] = v;
        offs[node] = bs + loc[t];
    }
}

// ---------------- MFMA dual GEMM: [P|Q] = A @ [Wl;Wr]^T ----------------
// Wave computes 16 rows x 64 cols (half=0 -> P, half=1 -> Q), both bf16 out.
// B-frags: read f32 W rows once per wave, pack to bf16 registers.
// A is f32 (layer 1, cvt in-flight) or bf16 (layer 2).

template <int K, bool AF32>
__global__ __launch_bounds__(256, 2)
void gemm_mfma(const void* __restrict__ Xv, const float* __restrict__ Wl,
               const float* __restrict__ Wr, unsigned short* __restrict__ Pb,
               unsigned short* __restrict__ Qb, int N) {
    const int lane = threadIdx.x & 63;
    const int m = lane & 15;        // row (A) / col (B) within tile
    const int q = lane >> 4;        // k-quad
    const int gw = blockIdx.x * 4 + (threadIdx.x >> 6);
    const int half = gw & 1;        // 0 -> P, 1 -> Q
    constexpr int KB = K / 32;

    const float* Wh = half ? Wr : Wl;
    short8 bf[KB][4];
#pragma unroll
    for (int kb = 0; kb < KB; ++kb)
#pragma unroll
        for (int ct = 0; ct < 4; ++ct) {
            int c = ct * 16 + m;
            const float* wp = Wh + (size_t)c * K + kb * 32 + q * 8;
            float4 w0 = *(const float4*)wp;
            float4 w1 = *(const float4*)(wp + 4);
            union { unsigned u[4]; short8 s; } cv;
            cv.u[0] = pack_bf2(w0.x, w0.y);
            cv.u[1] = pack_bf2(w0.z, w0.w);
            cv.u[2] = pack_bf2(w1.x, w1.y);
            cv.u[3] = pack_bf2(w1.z, w1.w);
            bf[kb][ct] = cv.s;
        }

    unsigned short* dstp = half ? Qb : Pb;
    const int ntiles = (N + 15) >> 4;
    const int stride = gridDim.x * 2;  // waves per half
    for (int t = gw >> 1; t < ntiles; t += stride) {
        const int r0 = t << 4;
        int rr = r0 + m;
        if (rr >= N) rr = N - 1;
        floatx4 acc[4];
#pragma unroll
        for (int ct = 0; ct < 4; ++ct) acc[ct] = (floatx4){0.f, 0.f, 0.f, 0.f};

#pragma unroll
        for (int kb = 0; kb < KB; ++kb) {
            short8 a;
            if (AF32) {
                const float* xp = (const float*)Xv + (size_t)rr * K + kb * 32 + q * 8;
                float4 x0 = *(const float4*)xp;
                float4 x1 = *(const float4*)(xp + 4);
                union { unsigned u[4]; short8 s; } cv;
                cv.u[0] = pack_bf2(x0.x, x0.y);
                cv.u[1] = pack_bf2(x0.z, x0.w);
                cv.u[2] = pack_bf2(x1.x, x1.y);
                cv.u[3] = pack_bf2(x1.z, x1.w);
                a = cv.s;
            } else {
                a = *(const short8*)((const unsigned short*)Xv + (size_t)rr * K + kb * 32 + q * 8);
            }
#pragma unroll
            for (int ct = 0; ct < 4; ++ct)
                acc[ct] = __builtin_amdgcn_mfma_f32_16x16x32_bf16(a, bf[kb][ct], acc[ct], 0, 0, 0);
        }

        // C/D: col = ct*16 + m, row = r0 + q*4 + i
#pragma unroll
        for (int i = 0; i < 4; ++i) {
            int row = r0 + q * 4 + i;
            if (row < N) {
#pragma unroll
                for (int ct = 0; ct < 4; ++ct)
                    dstp[(size_t)row * HID + ct * 16 + m] = f2bf(acc[ct][i]);
            }
        }
    }
}

// ------- aggregation: H = relu(mean_{s in N(n)} P[s] + bias + Q[n]) -------
// 8 nodes per wave (8 lanes/node), lane = uint4 = 8 bf16 channels.
// Packed cvt + float2 accumulators; 4-deep unroll (best measured).

__global__ __launch_bounds__(256)
void k_agg(const uint4* __restrict__ P8, const uint2* __restrict__ Qb4,
           const float4* __restrict__ bias4, const int* __restrict__ offs,
           const int* __restrict__ deg, const int* __restrict__ sorted,
           uint4* __restrict__ H8, int N) {
    int node = blockIdx.x * 32 + (threadIdx.x >> 3);
    int c8 = threadIdx.x & 7;
    if (node >= N) return;
    int off = offs[node];
    int c = deg[node];
    float2 a[4];
#pragma unroll
    for (int j = 0; j < 4; ++j) a[j] = make_float2(0.f, 0.f);
    int i = 0;
    for (; i + 3 < c; i += 4) {
        int s0 = sorted[off + i];
        int s1 = sorted[off + i + 1];
        int s2 = sorted[off + i + 2];
        int s3 = sorted[off + i + 3];
        uint4 u0 = P8[(size_t)s0 * 8 + c8];
        uint4 u1 = P8[(size_t)s1 * 8 + c8];
        uint4 u2 = P8[(size_t)s2 * 8 + c8];
        uint4 u3 = P8[(size_t)s3 * 8 + c8];
        accp(a, u0); accp(a, u1); accp(a, u2); accp(a, u3);
    }
    for (; i < c; ++i) accp(a, P8[(size_t)sorted[off + i] * 8 + c8]);

    float inv = 1.0f / (float)(c > 0 ? c : 1);
    float4 b0 = bias4[c8 * 2], b1 = bias4[c8 * 2 + 1];
    uint2 q0 = Qb4[(size_t)node * 16 + c8 * 2];
    uint2 q1 = Qb4[(size_t)node * 16 + c8 * 2 + 1];
    float2 r0 = bfx2(q0.x), r1 = bfx2(q0.y), r2 = bfx2(q1.x), r3 = bfx2(q1.y);
    float v0 = a[0].x * inv + b0.x + r0.x;
    float v1 = a[0].y * inv + b0.y + r0.y;
    float v2 = a[1].x * inv + b0.z + r1.x;
    float v3 = a[1].y * inv + b0.w + r1.y;
    float v4 = a[2].x * inv + b1.x + r2.x;
    float v5 = a[2].y * inv + b1.y + r2.y;
    float v6 = a[3].x * inv + b1.z + r3.x;
    float v7 = a[3].y * inv + b1.w + r3.y;
    v0 = fmaxf(v0, 0.f); v1 = fmaxf(v1, 0.f); v2 = fmaxf(v2, 0.f); v3 = fmaxf(v3, 0.f);
    v4 = fmaxf(v4, 0.f); v5 = fmaxf(v5, 0.f); v6 = fmaxf(v6, 0.f); v7 = fmaxf(v7, 0.f);
    uint4 hp;
    hp.x = pack_bf2(v0, v1);
    hp.y = pack_bf2(v2, v3);
    hp.z = pack_bf2(v4, v5);
    hp.w = pack_bf2(v6, v7);
    H8[(size_t)node * 8 + c8] = hp;
}

// ---------------- query: out[q] = sigmoid(sum_c Z[s][c]*Z[d][c]) ----------------
// 8 queries per wave (8 lanes each), uint4 bf16x8 loads, packed cvt + fma.

__global__ __launch_bounds__(256)
void k_query(const uint4* __restrict__ Z8, const int* __restrict__ src,
             const int* __restrict__ dst, float* __restrict__ out, int Q) {
    int qi = blockIdx.x * 32 + (threadIdx.x >> 3);
    int c8 = threadIdx.x & 7;
    if (qi >= Q) return;
    int s = src[qi];
    int d = dst[qi];
    uint4 us = Z8[(size_t)s * 8 + c8];
    uint4 ud = Z8[(size_t)d * 8 + c8];
    float2 p0 = bfx2(us.x), p1 = bfx2(us.y), p2 = bfx2(us.z), p3 = bfx2(us.w);
    float2 t0 = bfx2(ud.x), t1 = bfx2(ud.y), t2 = bfx2(ud.z), t3 = bfx2(ud.w);
    float2 acc2 = make_float2(p0.x * t0.x, p0.y * t0.y);
    acc2.x = fmaf(p1.x, t1.x, acc2.x); acc2.y = fmaf(p1.y, t1.y, acc2.y);
    acc2.x = fmaf(p2.x, t2.x, acc2.x); acc2.y = fmaf(p2.y, t2.y, acc2.y);
    acc2.x = fmaf(p3.x, t3.x, acc2.x); acc2.y = fmaf(p3.y, t3.y, acc2.y);
    float v = acc2.x + acc2.y;
#pragma unroll
    for (int mres = 4; mres > 0; mres >>= 1) v += __shfl_xor(v, mres, 64);
    if (c8 == 0) out[qi] = 1.0f / (1.0f + __expf(-v));
}

// ---------------- launch ----------------

extern "C" void kernel_launch(void* const* d_in, const int* in_sizes, int n_in,
                              void* d_out, int out_size, void* d_ws, size_t ws_size,
                              hipStream_t stream) {
    const float* x    = (const float*)d_in[0];
    const int*   ei   = (const int*)d_in[1];
    const int*   qsrc = (const int*)d_in[2];
    const int*   qdst = (const int*)d_in[3];
    const float* Wl1  = (const float*)d_in[4];
    const float* bl1  = (const float*)d_in[5];
    const float* Wr1  = (const float*)d_in[6];
    const float* Wl2  = (const float*)d_in[7];
    const float* bl2  = (const float*)d_in[8];
    const float* Wr2  = (const float*)d_in[9];
    float* out = (float*)d_out;

    const int N = in_sizes[0] / 128;  // IN_CH = 128
    const int E = in_sizes[1] / 2;
    const int Q = in_sizes[2];

    const int* esrc = ei;
    const int* edst = ei + E;

    // workspace layout (no aliasing; ws is plenty)
    unsigned short* Pb = (unsigned short*)d_ws;         // N x 64 bf16 messages
    unsigned short* Qb = Pb + (size_t)N * HID;          // N x 64 bf16 root
    unsigned short* Hb = Qb + (size_t)N * HID;          // N x 64 bf16 h
    unsigned short* Zb = Hb + (size_t)N * HID;          // N x 64 bf16 z
    int* deg_c  = (int*)(Zb + (size_t)N * HID);         // N
    int* offs   = deg_c + N;                            // N
    int* total  = offs + N;                             // NB_MAX
    int* base   = total + NB_MAX;                       // NB_MAX
    int* sorted = base + NB_MAX;                        // E
    int* cnt    = sorted + E;                           // NB_MAX*G_BLK
    int* ebuf   = cnt + (size_t)NB_MAX * G_BLK;         // E

    const int NB = (N + 255) >> 8;            // buckets of 256 nodes (<= NB_MAX)
    const int CH = (E + G_BLK - 1) / G_BLK;   // edges per bucket-pass block
    const int gG = 640;                       // grid-stride MFMA gemm
    const int gA = (N + 31) / 32;             // 8 nodes/wave, 4 waves/block
    const int gQ = (Q + 31) / 32;

    // CSR build: zero global atomics
    k_bhist<<<G_BLK, 256, 0, stream>>>(edst, cnt, E, NB, CH);
    k_bscan1<<<(NB + 3) / 4, 256, 0, stream>>>(cnt, total, NB);
    k_bscan2<<<1, 512, 0, stream>>>(total, base, NB);
    k_bscatter<<<G_BLK, 256, 0, stream>>>(esrc, edst, cnt, base, ebuf, E, NB, CH);
    k_bfinal<<<NB, 256, 0, stream>>>(ebuf, total, base, sorted, deg_c, offs, N);

    // layer 1: Pb = bf16(x@Wl1^T), Qb = bf16(x@Wr1^T); Hb = bf16(relu(mean+b+Qb))
    gemm_mfma<128, true><<<gG, 256, 0, stream>>>(x, Wl1, Wr1, Pb, Qb, N);
    k_agg<<<gA, 256, 0, stream>>>((const uint4*)Pb, (const uint2*)Qb,
                                  (const float4*)bl1, offs, deg_c, sorted,
                                  (uint4*)Hb, N);

    // layer 2: Pb = bf16(Hb@Wl2^T), Qb = bf16(Hb@Wr2^T); Zb = bf16(relu(mean+b+Qb))
    gemm_mfma<64, false><<<gG, 256, 0, stream>>>(Hb, Wl2, Wr2, Pb, Qb, N);
    k_agg<<<gA, 256, 0, stream>>>((const uint4*)Pb, (const uint2*)Qb,
                                  (const float4*)bl2, offs, deg_c, sorted,
                                  (uint4*)Zb, N);

    // queries
    k_query<<<gQ, 256, 0, stream>>>((const uint4*)Zb, qsrc, qdst, out, Q);
}